// Round 1
// baseline (528.145 us; speedup 1.0000x reference)
//
#include <hip/hip_runtime.h>

// CIN layers: Xn[b,h,d] = sum_{j,k} W[h,j,k] * X0[b,j,d] * Xi[b,k,d] + bias[h]
// Factored:   Y[h,j,d]  = sum_k Wbf16[h,j,k] * Xibf16[b,k,d]   (MFMA 16x16x32 bf16)
//             Xn[b,h,d] = sum_j X0bf16[b,j,d] * Y[h,j,d] + bias (f32 FMA epilogue)
// Output res[b, L*128+h] = sum_d Xn[b,h,d]  (shfl reduce over the 16 d-lanes)

#define NB_F0 39
#define NB_H  128
#define NB_D  16
#define NB_B  4096

typedef float f32x4 __attribute__((ext_vector_type(4)));
typedef short s16x8 __attribute__((ext_vector_type(8)));

__device__ __forceinline__ unsigned short rne_bf16(float f) {
  union { float f; unsigned u; } v; v.f = f;
  return (unsigned short)((v.u + 0x7fffu + ((v.u >> 16) & 1u)) >> 16);
}
__device__ __forceinline__ float bf16_to_f32(unsigned short s) {
  union { unsigned u; float f; } v; v.u = ((unsigned)s) << 16;
  return v.f;
}

// X0 f32 [B][39][16] -> X0T bf16 [B][16][64], zero-padded j>=39
__global__ void prep_x0_kernel(const float* __restrict__ X0g,
                               unsigned short* __restrict__ X0T) {
  const int b = blockIdx.x;
  const int t = threadIdx.x;
  const int d  = t >> 4;
  const int k4 = (t & 15) << 2;
  unsigned short vv[4];
#pragma unroll
  for (int i = 0; i < 4; ++i) {
    const int k = k4 + i;
    vv[i] = (k < NB_F0) ? rne_bf16(X0g[(size_t)b * (NB_F0 * 16) + k * 16 + d])
                        : (unsigned short)0;
  }
  ushort4 pk; pk.x = vv[0]; pk.y = vv[1]; pk.z = vv[2]; pk.w = vv[3];
  *(ushort4*)&X0T[((size_t)b * 16 + d) * 64 + k4] = pk;
}

// W f32 [128][39*Fi] -> Wp bf16 [39][128][Fi_pad], k' chunks (8 elems) XOR-swizzled
// by (h & SW) so LDS A-fragment reads are conflict-free. Pad k'>=Fi with 0.
__global__ void prep_w_kernel(const float* __restrict__ Wsrc,
                              unsigned short* __restrict__ Wdst,
                              int Fi, int Fi_pad, int SW, int total) {
  int idx = blockIdx.x * 256 + threadIdx.x;
  if (idx >= total) return;
  int j   = idx / (NB_H * Fi_pad);
  int rem = idx - j * (NB_H * Fi_pad);
  int h   = rem / Fi_pad;
  int kp  = rem - h * Fi_pad;
  int cp = kp >> 3, p = kp & 7;
  int kl = ((cp ^ (h & SW)) << 3) | p;
  unsigned short v = 0;
  if (kl < Fi) v = rne_bf16(Wsrc[(size_t)h * (NB_F0 * Fi) + j * Fi + kl]);
  Wdst[idx] = v;
}

// Main layer kernel. 256 threads = 4 waves; each wave owns 4 b's (block: 16 b).
// Grid 256 blocks. Stages = (half 0..1) x (j 0..38); W[j][64h][Fi_pad] chunk
// double-buffered in LDS; Xi B-fragments live in registers for whole kernel.
template <int FI_PAD, bool STORE_XN>
__global__ __launch_bounds__(256, 1) void cin_layer(
    const unsigned short* __restrict__ Wp,   // [39][128][FI_PAD] bf16 swizzled
    const unsigned short* __restrict__ XiT,  // [B][16][FI_PAD] bf16
    const unsigned short* __restrict__ X0T,  // [B][16][64] bf16
    const float* __restrict__ bias,          // [128]
    unsigned short* __restrict__ XnT,        // [B][16][128] bf16 (or unused)
    float* __restrict__ outp)                // d_out + layer*128, stride 384
{
  constexpr int KC = FI_PAD / 32;          // mfma K-chunks per j
  constexpr int SW = (FI_PAD / 8) - 1;     // swizzle mask
  constexpr int STAGE_SH = 64 * FI_PAD;    // ushorts per staged W chunk
  constexpr int NIT = (STAGE_SH * 2) / 4096;  // 1KB copy instrs per wave

  __shared__ unsigned short Wlds[2][STAGE_SH];
  __shared__ unsigned short x0s[16][16 * 41];  // [bi][d*41+j], stride 41: no bank conflict

  const int tid  = threadIdx.x;
  const int lane = tid & 63;
  const int wv   = tid >> 6;
  const int q    = lane >> 4;
  const int col  = lane & 15;
  const int bblk  = blockIdx.x * 16;
  const int bwave = bblk + wv * 4;

  // stage X0 (bf16) into LDS for the stage-2 multiply
  for (int idx = tid; idx < 16 * 16 * NB_F0; idx += 256) {
    int bi  = idx / (16 * NB_F0);
    int rem = idx - bi * (16 * NB_F0);
    int d = rem / NB_F0;
    int j = rem - d * NB_F0;
    x0s[bi][d * 41 + j] = X0T[((size_t)(bblk + bi) * 16 + d) * 64 + j];
  }

  // B fragments: Xi[k = kc*32 + q*8 + i][n = d = col] for each of this wave's 4 b's
  s16x8 bf[4][KC];
#pragma unroll
  for (int bi = 0; bi < 4; ++bi)
#pragma unroll
    for (int kc = 0; kc < KC; ++kc) {
      const unsigned short* src =
          XiT + ((size_t)(bwave + bi) * 16 + col) * FI_PAD + kc * 32 + q * 8;
      bf[bi][kc] = *(const s16x8*)src;
    }

  f32x4 Xacc[4][4];  // [ht][bi] output tile accumulators for current half
#pragma unroll
  for (int ht = 0; ht < 4; ++ht)
#pragma unroll
    for (int bi = 0; bi < 4; ++bi) Xacc[ht][bi] = f32x4{0.f, 0.f, 0.f, 0.f};

  const int wshare = (STAGE_SH * 2) / 4;  // staging bytes per wave
  uint4 stg[NIT];

  auto gload = [&](int s) {
    int half = (s >= NB_F0) ? 1 : 0;
    int j = s - half * NB_F0;
    const char* gsrc = (const char*)Wp +
        ((size_t)(j * NB_H + half * 64) * FI_PAD) * 2 + wv * wshare + lane * 16;
#pragma unroll
    for (int it = 0; it < NIT; ++it) stg[it] = *(const uint4*)(gsrc + it * 1024);
  };
  auto sstore = [&](int buf) {
    char* dst = (char*)&Wlds[buf][0] + wv * wshare + lane * 16;
#pragma unroll
    for (int it = 0; it < NIT; ++it) *(uint4*)(dst + it * 1024) = stg[it];
  };

  gload(0);
  sstore(0);

  const int S = 2 * NB_F0;
  for (int s = 0; s < S; ++s) {
    __syncthreads();                 // buf[s&1] ready for everyone
    if (s + 1 < S) gload(s + 1);     // global loads overlap this stage's compute

    const int half = (s >= NB_F0) ? 1 : 0;
    const int j = s - half * NB_F0;
    const unsigned short* wb = &Wlds[s & 1][0];

    float x0v[4];
#pragma unroll
    for (int bi = 0; bi < 4; ++bi)
      x0v[bi] = bf16_to_f32(x0s[wv * 4 + bi][col * 41 + j]);

#pragma unroll
    for (int ht = 0; ht < 4; ++ht) {
      f32x4 y[4];
#pragma unroll
      for (int bi = 0; bi < 4; ++bi) y[bi] = f32x4{0.f, 0.f, 0.f, 0.f};
#pragma unroll
      for (int kc = 0; kc < KC; ++kc) {
        const int c0 = kc * 4 + q;
        const s16x8 af = *(const s16x8*)&wb[(ht * 16 + col) * FI_PAD +
                                            ((c0 ^ (col & SW)) << 3)];
#pragma unroll
        for (int bi = 0; bi < 4; ++bi)
          y[bi] = __builtin_amdgcn_mfma_f32_16x16x32_bf16(af, bf[bi][kc], y[bi],
                                                          0, 0, 0);
      }
#pragma unroll
      for (int bi = 0; bi < 4; ++bi)
#pragma unroll
        for (int r = 0; r < 4; ++r) Xacc[ht][bi][r] += x0v[bi] * y[bi][r];
    }

    if (s + 1 < S) sstore((s + 1) & 1);  // fills the other buffer; next barrier syncs

    if (j == NB_F0 - 1) {  // epilogue for this half (64 h)
#pragma unroll
      for (int ht = 0; ht < 4; ++ht) {
        const int hbase = half * 64 + ht * 16 + q * 4;
        const float* bp = bias + hbase;
        float b4[4] = {bp[0], bp[1], bp[2], bp[3]};
#pragma unroll
        for (int bi = 0; bi < 4; ++bi) {
          const int b = bwave + bi;
          float v[4];
#pragma unroll
          for (int r = 0; r < 4; ++r) v[r] = Xacc[ht][bi][r] + b4[r];
          if (STORE_XN) {
            ushort4 pk;
            pk.x = rne_bf16(v[0]); pk.y = rne_bf16(v[1]);
            pk.z = rne_bf16(v[2]); pk.w = rne_bf16(v[3]);
            *(ushort4*)&XnT[((size_t)b * 16 + col) * NB_H + hbase] = pk;
          }
#pragma unroll
          for (int m = 1; m < 16; m <<= 1)
#pragma unroll
            for (int r = 0; r < 4; ++r) v[r] += __shfl_xor(v[r], m);
          if (col == 0) {
            float4 o; o.x = v[0]; o.y = v[1]; o.z = v[2]; o.w = v[3];
            *(float4*)&outp[(size_t)b * 384 + hbase] = o;
          }
          Xacc[ht][bi] = f32x4{0.f, 0.f, 0.f, 0.f};
        }
      }
    }
  }
}

extern "C" void kernel_launch(void* const* d_in, const int* in_sizes, int n_in,
                              void* d_out, int out_size, void* d_ws, size_t ws_size,
                              hipStream_t stream) {
  (void)in_sizes; (void)n_in; (void)out_size; (void)ws_size;
  const float* X0g = (const float*)d_in[0];
  const float* W0  = (const float*)d_in[1];
  const float* b0  = (const float*)d_in[2];
  const float* W1  = (const float*)d_in[3];
  const float* b1  = (const float*)d_in[4];
  const float* W2  = (const float*)d_in[5];
  const float* b2  = (const float*)d_in[6];
  float* out = (float*)d_out;

  char* p = (char*)d_ws;
  unsigned short* X0T = (unsigned short*)p; p += (size_t)NB_B * 16 * 64 * 2;
  unsigned short* X1T = (unsigned short*)p; p += (size_t)NB_B * 16 * 128 * 2;
  unsigned short* X2T = (unsigned short*)p; p += (size_t)NB_B * 16 * 128 * 2;
  unsigned short* Wp0 = (unsigned short*)p; p += (size_t)NB_F0 * 128 * 64 * 2;
  unsigned short* Wp1 = (unsigned short*)p; p += (size_t)NB_F0 * 128 * 128 * 2;
  unsigned short* Wp2 = (unsigned short*)p; p += (size_t)NB_F0 * 128 * 128 * 2;

  hipLaunchKernelGGL(prep_x0_kernel, dim3(NB_B), dim3(256), 0, stream, X0g, X0T);
  const int tw0  = NB_F0 * 128 * 64;
  const int tw12 = NB_F0 * 128 * 128;
  hipLaunchKernelGGL(prep_w_kernel, dim3((tw0 + 255) / 256), dim3(256), 0, stream,
                     W0, Wp0, 39, 64, 7, tw0);
  hipLaunchKernelGGL(prep_w_kernel, dim3((tw12 + 255) / 256), dim3(256), 0, stream,
                     W1, Wp1, 128, 128, 15, tw12);
  hipLaunchKernelGGL(prep_w_kernel, dim3((tw12 + 255) / 256), dim3(256), 0, stream,
                     W2, Wp2, 128, 128, 15, tw12);

  hipLaunchKernelGGL((cin_layer<64, true>),   dim3(256), dim3(256), 0, stream,
                     Wp0, X0T, X0T, b0, X1T, out + 0);
  hipLaunchKernelGGL((cin_layer<128, true>),  dim3(256), dim3(256), 0, stream,
                     Wp1, X1T, X0T, b1, X2T, out + 128);
  hipLaunchKernelGGL((cin_layer<128, false>), dim3(256), dim3(256), 0, stream,
                     Wp2, X2T, X0T, b2, (unsigned short*)nullptr, out + 256);
}